// Round 2
// 119.762 us; speedup vs baseline: 1.0210x; 1.0210x over previous
//
#include <hip/hip_runtime.h>
#include <hip/hip_bf16.h>

#define B_ 4
#define T_ 256
#define S_ 256
#define D_ 512
#define TB 2   // t's per attention block

typedef __bf16 bf16x8 __attribute__((ext_vector_type(8)));
typedef float  floatx4 __attribute__((ext_vector_type(4)));

#define C2F 2.885390081777926f  // 2*log2(e)

static __device__ __forceinline__ unsigned short f2bf(float x) {
    __hip_bfloat16 h = __float2bfloat16(x);
    return *reinterpret_cast<unsigned short*>(&h);
}
static __device__ __forceinline__ float asf(unsigned int u) {
    float f; __builtin_memcpy(&f, &u, 4); return f;
}
static __device__ __forceinline__ float clamp_pos(float x) {
    // keep strictly positive and finite: [1e-15, 1e15]
    return fminf(fmaxf(x, 1e-15f), 1e15f);
}

// ---------------------------------------------------------------------------
// Fragment-order layout (K=512 => 16 k-blocks of 32):
//   tile(mblk,kblk) = mblk*16 + kblk;  lane = (m&15) | (((k>>3)&3)<<4)
//   addr = (tile*64 + lane)*8 + (k&7)
// ---------------------------------------------------------------------------

__global__ __launch_bounds__(256) void prep(
    const float* __restrict__ output, const float* __restrict__ context,
    const float* __restrict__ Wq, const float* __restrict__ Wc,
    const float* __restrict__ Wout,
    unsigned short* __restrict__ out_f, unsigned short* __restrict__ ctx_f,
    unsigned short* __restrict__ Wq_f, unsigned short* __restrict__ Wc_f,
    unsigned short* __restrict__ WoT_f, unsigned short* __restrict__ WoB_f)
{
    const int tid = threadIdx.x;
    const int z = blockIdx.z;

    if (z >= 4) {
        const float* src = (z == 4) ? output : context;
        unsigned short* dst = (z == 4) ? out_f : ctx_f;
        const int bid  = blockIdx.y * 16 + blockIdx.x;   // 0..255
        const int tile = bid * 4 + (tid >> 6);           // 0..1023
        const int lane = tid & 63;
        const int mblk = tile >> 4, kblk = tile & 15;
        const float* s = src + (size_t)(mblk * 16 + (lane & 15)) * 512
                             + kblk * 32 + (lane >> 4) * 8;
        float4 a = *(const float4*)s;
        float4 b = *(const float4*)(s + 4);
        uint4 pk;
        pk.x = (unsigned)f2bf(a.x) | ((unsigned)f2bf(a.y) << 16);
        pk.y = (unsigned)f2bf(a.z) | ((unsigned)f2bf(a.w) << 16);
        pk.z = (unsigned)f2bf(b.x) | ((unsigned)f2bf(b.y) << 16);
        pk.w = (unsigned)f2bf(b.z) | ((unsigned)f2bf(b.w) << 16);
        *(uint4*)(dst + (size_t)tile * 512 + lane * 8) = pk;
        return;
    }

    const float* W; unsigned short* WF; int krow0;
    if      (z == 0) { W = Wq;   WF = Wq_f;  krow0 = 0;   }
    else if (z == 1) { W = Wc;   WF = Wc_f;  krow0 = 0;   }
    else if (z == 2) { W = Wout; WF = WoT_f; krow0 = 0;   }
    else             { W = Wout; WF = WoB_f; krow0 = 512; }

    const int n0 = blockIdx.x * 32;
    const int k0 = blockIdx.y * 32;

    __shared__ float tile[32][33];
    const int c = tid & 31, r = tid >> 5;
    #pragma unroll
    for (int i = 0; i < 4; ++i)
        tile[r + 8 * i][c] = W[(size_t)(krow0 + k0 + r + 8 * i) * 512 + n0 + c];
    __syncthreads();
    #pragma unroll
    for (int i = 0; i < 4; ++i) {
        const int n = n0 + r + 8 * i;
        const int k = k0 + c;
        const int tl = (n >> 4) * 16 + (k >> 5);
        const int ln = (n & 15) | (((k >> 3) & 3) << 4);
        WF[((size_t)tl * 64 + ln) * 8 + (k & 7)] = f2bf(tile[c][r + 8 * i]);
    }
}

// ---------------------------------------------------------------------------
// MFMA bf16 GEMM from fragment-order inputs. Epilogue modes:
//   1: H = clamp(exp2(C2F*(acc+bq[col])))  fp32 (B,T,D)       (h = e^{2w})
//   3: G = clamp(exp2(-C2F*acc))           fp32 [b][d>>2][s][d&3] (g = e^{-2u})
//   4: fp32 acc + aux[col]                 (OB = output@Wout_bot + bout)
//   5: bf16 acc, natural [row][col]        (CWb = context@Wout_top)
// ---------------------------------------------------------------------------
struct GArgs {
    const unsigned short* Af;
    const unsigned short* Bf;
    const float* aux;    // bias
    void* C;
    int mode;
};

__global__ __launch_bounds__(256) void gemm2(GArgs g0, GArgs g1, GArgs g2, GArgs g3)
{
    const int z = blockIdx.z;
    GArgs g = (z == 0) ? g0 : (z == 1) ? g1 : (z == 2) ? g2 : g3;

    const int tid  = threadIdx.x;
    const int wave = tid >> 6, lane = tid & 63;
    const int l15  = lane & 15, quad = lane >> 4;
    const int mblk = blockIdx.y * 4 + wave;      // 0..63
    const int nb0  = blockIdx.x * 2;             // 0..30

    const unsigned short* Ap  = g.Af + ((size_t)mblk * 16 * 64 + lane) * 8;
    const unsigned short* Bp0 = g.Bf + ((size_t)nb0 * 16 * 64 + lane) * 8;
    const unsigned short* Bp1 = Bp0 + (size_t)16 * 64 * 8;

    floatx4 acc[2];
    acc[0] = (floatx4){0.f, 0.f, 0.f, 0.f};
    acc[1] = (floatx4){0.f, 0.f, 0.f, 0.f};

    #pragma unroll 4
    for (int k = 0; k < 16; ++k) {
        bf16x8 a  = *(const bf16x8*)(Ap  + k * 512);
        bf16x8 b0 = *(const bf16x8*)(Bp0 + k * 512);
        bf16x8 b1 = *(const bf16x8*)(Bp1 + k * 512);
        acc[0] = __builtin_amdgcn_mfma_f32_16x16x32_bf16(a, b0, acc[0], 0, 0, 0);
        acc[1] = __builtin_amdgcn_mfma_f32_16x16x32_bf16(a, b1, acc[1], 0, 0, 0);
    }

    #pragma unroll
    for (int ni = 0; ni < 2; ++ni) {
        const int col = (nb0 + ni) * 16 + l15;
        const int rbase = mblk * 16 + quad * 4;
        if (g.mode == 1) {
            float* Cf = (float*)g.C;
            float bv = g.aux[col];
            #pragma unroll
            for (int r = 0; r < 4; ++r) {
                float hh = __builtin_amdgcn_exp2f(C2F * (acc[ni][r] + bv));
                Cf[(size_t)(rbase + r) * 512 + col] = clamp_pos(hh);
            }
        } else if (g.mode == 3) {
            float* Cf = (float*)g.C;
            #pragma unroll
            for (int r = 0; r < 4; ++r) {
                int row = rbase + r, bb = row >> 8, ss = row & 255;
                float gg = __builtin_amdgcn_exp2f(-C2F * acc[ni][r]);
                Cf[((size_t)(bb * 128 + (col >> 2)) * 256 + ss) * 4 + (col & 3)]
                    = clamp_pos(gg);
            }
        } else if (g.mode == 5) {
            unsigned short* Cb = (unsigned short*)g.C;
            #pragma unroll
            for (int r = 0; r < 4; ++r)
                Cb[(size_t)(rbase + r) * 512 + col] = f2bf(acc[ni][r]);
        } else {   // mode 4
            float* Cf = (float*)g.C;
            float bv = g.aux[col];
            #pragma unroll
            for (int r = 0; r < 4; ++r)
                Cf[(size_t)(rbase + r) * 512 + col] = acc[ni][r] + bv;
        }
    }
}

// ---------------------------------------------------------------------------
// Fused score + masked softmax + out-projection.
// Score via factorized sigmoid: v*r = v*G/(G+H), G=e^{-2u} (per s,d),
// H=e^{2w} (per t,d). Adjacent-d pairs combine with ONE rcp:
//   v0r0+v1r1 = (P0*D1 + P1*D0)/(D0*D1),  P_i=v_i*G_i,  D_i=G_i+H_i
// (P is t-independent -> computed once per pair, used for both t's.)
// No exp and 0.5 rcp per element in the hot loop (was 1 exp + 1 rcp).
// Softmax: p = exp2(-C2F*A) directly (shift-invariance), as before.
// ---------------------------------------------------------------------------
__global__ __launch_bounds__(1024) void attn_fused(
    const float* __restrict__ Hb,             // (B,T,D) fp32  e^{2w}
    const float* __restrict__ Gb,             // (B,D/4,S,4) fp32  e^{-2u}
    const unsigned short* __restrict__ CWb,   // (B,S,D) bf16
    const float* __restrict__ OB,             // (B,T,D) fp32
    const int*   __restrict__ mask,           // (B,S)
    const float* __restrict__ v,              // (D)
    float* __restrict__ attn_out,             // (B,T,S) fp32
    float* __restrict__ out)                  // (B,T,D) fp32
{
    const int bg  = blockIdx.x;
    const int b   = bg / (T_ / TB);
    const int t0  = (bg % (T_ / TB)) * TB;
    const int tid = threadIdx.x;
    const int s   = tid & 255;
    const int h   = tid >> 8;    // 0..3  (d-quarter in score, s-quarter in proj)

    __shared__ float  w_s[TB][D_];       // 4 KB (H rows)
    __shared__ float  v_s[D_];           // 2 KB
    __shared__ float2 part[4][256];      // 8 KB
    __shared__ float2 wred[4];
    __shared__ float  a_s[TB][256];      // 2 KB
    __shared__ float  mixp[4][TB][D_];   // 16 KB

    if (tid < 512) {
        w_s[0][tid] = Hb[(size_t)(b * T_ + t0 + 0) * D_ + tid];
        w_s[1][tid] = Hb[(size_t)(b * T_ + t0 + 1) * D_ + tid];
        v_s[tid]    = v[tid];
    }
    __syncthreads();

    float acc0 = 0.f, acc1 = 0.f;
    const float* gbase = Gb + ((size_t)(b * 128 + h * 32) * 256 + s) * 4;

    #pragma unroll 4
    for (int dd = 0; dd < 16; ++dd) {
        float4 ga = *(const float4*)(gbase + dd * 2048);          // coalesced 16B
        float4 gb = *(const float4*)(gbase + dd * 2048 + 1024);   // coalesced 16B
        const int dbase = (h * 16 + dd) * 8;
        float4 va  = *(const float4*)&v_s[dbase];
        float4 vb  = *(const float4*)&v_s[dbase + 4];
        float4 h0a = *(const float4*)&w_s[0][dbase];
        float4 h0b = *(const float4*)&w_s[0][dbase + 4];
        float4 h1a = *(const float4*)&w_s[1][dbase];
        float4 h1b = *(const float4*)&w_s[1][dbase + 4];
        float G[8]  = {ga.x,  ga.y,  ga.z,  ga.w,  gb.x,  gb.y,  gb.z,  gb.w};
        float V[8]  = {va.x,  va.y,  va.z,  va.w,  vb.x,  vb.y,  vb.z,  vb.w};
        float H0[8] = {h0a.x, h0a.y, h0a.z, h0a.w, h0b.x, h0b.y, h0b.z, h0b.w};
        float H1[8] = {h1a.x, h1a.y, h1a.z, h1a.w, h1b.x, h1b.y, h1b.z, h1b.w};
        #pragma unroll
        for (int p = 0; p < 4; ++p) {
            float G0 = G[2 * p], G1 = G[2 * p + 1];
            float P0 = V[2 * p] * G0, P1 = V[2 * p + 1] * G1;   // t-independent
            float D00 = G0 + H0[2 * p], D01 = G1 + H0[2 * p + 1];
            acc0 = fmaf(fmaf(P0, D01, P1 * D00),
                        __builtin_amdgcn_rcpf(D00 * D01), acc0);
            float D10 = G0 + H1[2 * p], D11 = G1 + H1[2 * p + 1];
            acc1 = fmaf(fmaf(P0, D11, P1 * D10),
                        __builtin_amdgcn_rcpf(D10 * D11), acc1);
        }
    }
    part[h][s] = make_float2(acc0, acc1);
    __syncthreads();

    float p0 = 0.f, p1 = 0.f;
    if (tid < 256) {
        float A0 = part[0][tid].x + part[1][tid].x + part[2][tid].x + part[3][tid].x;
        float A1 = part[0][tid].y + part[1][tid].y + part[2][tid].y + part[3][tid].y;
        float keep = 1.0f - (float)mask[b * S_ + tid];
        p0 = __builtin_amdgcn_exp2f(-C2F * A0) * keep;
        p1 = __builtin_amdgcn_exp2f(-C2F * A1) * keep;
        float s0 = p0, s1 = p1;
        #pragma unroll
        for (int off = 1; off < 64; off <<= 1) {
            s0 += __shfl_xor(s0, off);
            s1 += __shfl_xor(s1, off);
        }
        if ((tid & 63) == 0) wred[tid >> 6] = make_float2(s0, s1);
    }
    __syncthreads();

    if (tid < 256) {
        float den0 = wred[0].x + wred[1].x + wred[2].x + wred[3].x;
        float den1 = wred[0].y + wred[1].y + wred[2].y + wred[3].y;
        float a0 = p0 * __builtin_amdgcn_rcpf(den0);
        float a1 = p1 * __builtin_amdgcn_rcpf(den1);
        attn_out[(size_t)(b * T_ + t0 + 0) * S_ + tid] = a0;
        attn_out[(size_t)(b * T_ + t0 + 1) * S_ + tid] = a1;
        a_s[0][tid] = a0;
        a_s[1][tid] = a1;
    }
    __syncthreads();

    // out-projection: thread (d2=tid&255 -> d={2d2,2d2+1}), s-quarter h
    const int d2 = tid & 255;
    const int sh = h * 64;
    const unsigned short* cw = CWb + ((size_t)(b * S_) + sh) * D_ + 2 * d2;
    float m[TB][2] = {};
    #pragma unroll 8
    for (int s2 = 0; s2 < 64; ++s2) {
        unsigned int cc = *(const unsigned int*)(cw + (size_t)s2 * D_);
        float c0 = asf(cc << 16), c1 = asf(cc & 0xffff0000u);
        #pragma unroll
        for (int t = 0; t < TB; ++t) {
            float a = a_s[t][sh + s2];
            m[t][0] = fmaf(a, c0, m[t][0]);
            m[t][1] = fmaf(a, c1, m[t][1]);
        }
    }
    #pragma unroll
    for (int t = 0; t < TB; ++t) {
        mixp[h][t][2 * d2]     = m[t][0];
        mixp[h][t][2 * d2 + 1] = m[t][1];
    }
    __syncthreads();

    {   // 1024 threads cover TB*512 outputs
        const int t = tid >> 9, d = tid & 511;
        size_t idx = (size_t)(b * T_ + t0 + t) * D_ + d;
        out[idx] = mixp[0][t][d] + mixp[1][t][d] + mixp[2][t][d] + mixp[3][t][d]
                 + OB[idx];
    }
}

extern "C" void kernel_launch(void* const* d_in, const int* in_sizes, int n_in,
                              void* d_out, int out_size, void* d_ws, size_t ws_size,
                              hipStream_t stream) {
    const float* output  = (const float*)d_in[0];
    const float* context = (const float*)d_in[1];
    const int*   mask    = (const int*)d_in[2];
    const float* Wq      = (const float*)d_in[3];
    const float* bq      = (const float*)d_in[4];
    const float* Wc      = (const float*)d_in[5];
    const float* v       = (const float*)d_in[6];
    const float* Wout    = (const float*)d_in[7];
    const float* bout    = (const float*)d_in[8];

    float* out  = (float*)d_out;                       // (B,T,D)
    float* attn = out + (size_t)B_ * T_ * D_;          // (B,T,S)

    char* ws = (char*)d_ws;
    float* Hb             = (float*)ws;                             // 2 MB
    float* OB             = (float*)(ws + (2u << 20));              // 2 MB
    float* Gb             = (float*)(ws + (4u << 20));              // 2 MB
    unsigned short* out_f = (unsigned short*)(ws + (6u << 20));     // 1 MB
    unsigned short* ctx_f = (unsigned short*)(ws + (7u << 20));     // 1 MB
    unsigned short* Wq_f  = (unsigned short*)(ws + (8u << 20));     // 0.5 MB
    unsigned short* Wc_f  = (unsigned short*)(ws + (8u << 20) + (512u << 10));
    unsigned short* WoT_f = (unsigned short*)(ws + (9u << 20));     // 0.5 MB
    unsigned short* WoB_f = (unsigned short*)(ws + (9u << 20) + (512u << 10));
    unsigned short* CWb   = (unsigned short*)(ws + (10u << 20));    // 1 MB

    dim3 blk(256);

    prep<<<dim3(16, 16, 6), blk, 0, stream>>>(
        output, context, Wq, Wc, Wout, out_f, ctx_f, Wq_f, Wc_f, WoT_f, WoB_f);

    // four independent GEMMs, one dispatch (z-slices), K=512 each:
    //   z0: Hb  = clamp(exp2(C2*(output@Wq + bq)))   [mode 1]
    //   z1: Gb  = clamp(exp2(-C2*(context@Wc))) perm [mode 3]
    //   z2: OB  = output@Wout_bot + bout             [mode 4]
    //   z3: CWb = bf16 context@Wout_top              [mode 5]
    GArgs gwq = { out_f, Wq_f,  bq,      Hb,  1 };
    GArgs guh = { ctx_f, Wc_f,  nullptr, Gb,  3 };
    GArgs gob = { out_f, WoB_f, bout,    OB,  4 };
    GArgs gcw = { ctx_f, WoT_f, nullptr, CWb, 5 };
    gemm2<<<dim3(16, 16, 4), blk, 0, stream>>>(gwq, guh, gob, gcw);

    attn_fused<<<dim3(B_ * T_ / TB), dim3(1024), 0, stream>>>(
        Hb, Gb, CWb, OB, mask, v, attn, out);
}

// Round 3
// 112.983 us; speedup vs baseline: 1.0823x; 1.0600x over previous
//
#include <hip/hip_runtime.h>
#include <hip/hip_bf16.h>

#define B_ 4
#define T_ 256
#define S_ 256
#define D_ 512
#define TB 2   // t's per attention block

typedef __bf16 bf16x8 __attribute__((ext_vector_type(8)));
typedef float  floatx4 __attribute__((ext_vector_type(4)));

#define C2F 2.885390081777926f  // 2*log2(e)

static __device__ __forceinline__ unsigned short f2bf(float x) {
    __hip_bfloat16 h = __float2bfloat16(x);
    return *reinterpret_cast<unsigned short*>(&h);
}
static __device__ __forceinline__ float asf(unsigned int u) {
    float f; __builtin_memcpy(&f, &u, 4); return f;
}
static __device__ __forceinline__ float clamp_pos(float x) {
    // keep strictly positive and finite: [1e-15, 1e15]
    return fminf(fmaxf(x, 1e-15f), 1e15f);
}

// ---------------------------------------------------------------------------
// Fragment-order layout (K=512 => 16 k-blocks of 32):
//   tile(mblk,kblk) = mblk*16 + kblk;  lane = (m&15) | (((k>>3)&3)<<4)
//   addr = (tile*64 + lane)*8 + (k&7)
// ---------------------------------------------------------------------------

__global__ __launch_bounds__(256) void prep(
    const float* __restrict__ output, const float* __restrict__ context,
    const float* __restrict__ Wq, const float* __restrict__ Wc,
    const float* __restrict__ Wout,
    unsigned short* __restrict__ out_f, unsigned short* __restrict__ ctx_f,
    unsigned short* __restrict__ Wq_f, unsigned short* __restrict__ Wc_f,
    unsigned short* __restrict__ WoT_f, unsigned short* __restrict__ WoB_f)
{
    const int tid = threadIdx.x;
    const int z = blockIdx.z;

    if (z >= 4) {
        const float* src = (z == 4) ? output : context;
        unsigned short* dst = (z == 4) ? out_f : ctx_f;
        const int bid  = blockIdx.y * 16 + blockIdx.x;   // 0..255
        const int tile = bid * 4 + (tid >> 6);           // 0..1023
        const int lane = tid & 63;
        const int mblk = tile >> 4, kblk = tile & 15;
        const float* s = src + (size_t)(mblk * 16 + (lane & 15)) * 512
                             + kblk * 32 + (lane >> 4) * 8;
        float4 a = *(const float4*)s;
        float4 b = *(const float4*)(s + 4);
        uint4 pk;
        pk.x = (unsigned)f2bf(a.x) | ((unsigned)f2bf(a.y) << 16);
        pk.y = (unsigned)f2bf(a.z) | ((unsigned)f2bf(a.w) << 16);
        pk.z = (unsigned)f2bf(b.x) | ((unsigned)f2bf(b.y) << 16);
        pk.w = (unsigned)f2bf(b.z) | ((unsigned)f2bf(b.w) << 16);
        *(uint4*)(dst + (size_t)tile * 512 + lane * 8) = pk;
        return;
    }

    const float* W; unsigned short* WF; int krow0;
    if      (z == 0) { W = Wq;   WF = Wq_f;  krow0 = 0;   }
    else if (z == 1) { W = Wc;   WF = Wc_f;  krow0 = 0;   }
    else if (z == 2) { W = Wout; WF = WoT_f; krow0 = 0;   }
    else             { W = Wout; WF = WoB_f; krow0 = 512; }

    const int n0 = blockIdx.x * 32;
    const int k0 = blockIdx.y * 32;

    __shared__ float tile[32][33];
    const int c = tid & 31, r = tid >> 5;
    #pragma unroll
    for (int i = 0; i < 4; ++i)
        tile[r + 8 * i][c] = W[(size_t)(krow0 + k0 + r + 8 * i) * 512 + n0 + c];
    __syncthreads();
    #pragma unroll
    for (int i = 0; i < 4; ++i) {
        const int n = n0 + r + 8 * i;
        const int k = k0 + c;
        const int tl = (n >> 4) * 16 + (k >> 5);
        const int ln = (n & 15) | (((k >> 3) & 3) << 4);
        WF[((size_t)tl * 64 + ln) * 8 + (k & 7)] = f2bf(tile[c][r + 8 * i]);
    }
}

// ---------------------------------------------------------------------------
// MFMA bf16 GEMM from fragment-order inputs. Epilogue modes:
//   1: H = clamp(exp2(C2F*(acc+bq[col])), 1e-15, 1e15)  fp32 (B,T,D)
//   3: W = clamp(exp2(+C2F*acc) * rcp(v[col]), +-1e20)  bf16
//      -> layout [b][d>>3][s][8]   (W = e^{2u}/v;  v*sigmoid = 1/(1/v + H*W))
//   4: fp32 acc + aux[col]                 (OB = output@Wout_bot + bout)
//   5: bf16 acc, natural [row][col]        (CWb = context@Wout_top)
// ---------------------------------------------------------------------------
struct GArgs {
    const unsigned short* Af;
    const unsigned short* Bf;
    const float* aux;    // bias (modes 1,4) or v (mode 3)
    void* C;
    int mode;
};

__global__ __launch_bounds__(256) void gemm2(GArgs g0, GArgs g1, GArgs g2, GArgs g3)
{
    const int z = blockIdx.z;
    GArgs g = (z == 0) ? g0 : (z == 1) ? g1 : (z == 2) ? g2 : g3;

    const int tid  = threadIdx.x;
    const int wave = tid >> 6, lane = tid & 63;
    const int l15  = lane & 15, quad = lane >> 4;
    const int mblk = blockIdx.y * 4 + wave;      // 0..63
    const int nb0  = blockIdx.x * 2;             // 0..30

    const unsigned short* Ap  = g.Af + ((size_t)mblk * 16 * 64 + lane) * 8;
    const unsigned short* Bp0 = g.Bf + ((size_t)nb0 * 16 * 64 + lane) * 8;
    const unsigned short* Bp1 = Bp0 + (size_t)16 * 64 * 8;

    floatx4 acc[2];
    acc[0] = (floatx4){0.f, 0.f, 0.f, 0.f};
    acc[1] = (floatx4){0.f, 0.f, 0.f, 0.f};

    #pragma unroll 4
    for (int k = 0; k < 16; ++k) {
        bf16x8 a  = *(const bf16x8*)(Ap  + k * 512);
        bf16x8 b0 = *(const bf16x8*)(Bp0 + k * 512);
        bf16x8 b1 = *(const bf16x8*)(Bp1 + k * 512);
        acc[0] = __builtin_amdgcn_mfma_f32_16x16x32_bf16(a, b0, acc[0], 0, 0, 0);
        acc[1] = __builtin_amdgcn_mfma_f32_16x16x32_bf16(a, b1, acc[1], 0, 0, 0);
    }

    #pragma unroll
    for (int ni = 0; ni < 2; ++ni) {
        const int col = (nb0 + ni) * 16 + l15;
        const int rbase = mblk * 16 + quad * 4;
        if (g.mode == 1) {
            float* Cf = (float*)g.C;
            float bv = g.aux[col];
            #pragma unroll
            for (int r = 0; r < 4; ++r) {
                float hh = __builtin_amdgcn_exp2f(C2F * (acc[ni][r] + bv));
                Cf[(size_t)(rbase + r) * 512 + col] = clamp_pos(hh);
            }
        } else if (g.mode == 3) {
            unsigned short* Cb = (unsigned short*)g.C;
            float rv = __builtin_amdgcn_rcpf(g.aux[col]);   // 1/v_col
            rv = fminf(fmaxf(rv, -1e30f), 1e30f);
            #pragma unroll
            for (int r = 0; r < 4; ++r) {
                int row = rbase + r, bb = row >> 8, ss = row & 255;
                float ww = __builtin_amdgcn_exp2f(C2F * acc[ni][r]) * rv;
                ww = fminf(fmaxf(ww, -1e20f), 1e20f);
                Cb[((size_t)(bb * 64 + (col >> 3)) * 256 + ss) * 8 + (col & 7)]
                    = f2bf(ww);
            }
        } else if (g.mode == 5) {
            unsigned short* Cb = (unsigned short*)g.C;
            #pragma unroll
            for (int r = 0; r < 4; ++r)
                Cb[(size_t)(rbase + r) * 512 + col] = f2bf(acc[ni][r]);
        } else {   // mode 4
            float* Cf = (float*)g.C;
            float bv = g.aux[col];
            #pragma unroll
            for (int r = 0; r < 4; ++r)
                Cf[(size_t)(rbase + r) * 512 + col] = acc[ni][r] + bv;
        }
    }
}

// ---------------------------------------------------------------------------
// Fused score + masked softmax + out-projection.
// Score: v*sigmoid(-2(w+u)) = 1/(1/v + H*W),  H=e^{2w} (t,d), W=e^{2u}/v (s,d).
// x = iv + H*W is single-signed (iv and H*W share v's sign) -> no
// cancellation, no zero crossing. Pair combine with ONE rcp:
//   1/x0 + 1/x1 = (x0+x1) * rcp(x0*x1)
// Hot loop per d-pair per t: 2 fma + 1 add + 1 mul + 1 rcp + 1 fma.
// W stream is bf16x8 (16B/lane coalesced, half the loads of fp32).
// Softmax: p = exp2(-C2F*A) directly (shift-invariance).
// XCD swizzle: 128 blocks/b -> chunk so each XCD works one b-half and its
// W/CW/H/OB streams (~1.5 MB) stay resident in that XCD's 4 MB L2.
// ---------------------------------------------------------------------------
__global__ __launch_bounds__(1024) void attn_fused(
    const float* __restrict__ Hb,             // (B,T,D) fp32  e^{2w}
    const unsigned short* __restrict__ Wb,    // (B,D/8,S,8) bf16  e^{2u}/v
    const unsigned short* __restrict__ CWb,   // (B,S,D) bf16
    const float* __restrict__ OB,             // (B,T,D) fp32
    const int*   __restrict__ mask,           // (B,S)
    const float* __restrict__ v,              // (D)
    float* __restrict__ attn_out,             // (B,T,S) fp32
    float* __restrict__ out)                  // (B,T,D) fp32
{
    // bijective XCD chunk swizzle (512 % 8 == 0)
    const int bid = blockIdx.x;
    const int bg  = (bid & 7) * (B_ * T_ / TB / 8) + (bid >> 3);
    const int b   = bg / (T_ / TB);
    const int t0  = (bg % (T_ / TB)) * TB;
    const int tid = threadIdx.x;
    const int s   = tid & 255;
    const int h   = tid >> 8;    // 0..3  (d-quarter in score, s-quarter in proj)

    __shared__ float  w_s[TB][D_];       // 4 KB (H rows)
    __shared__ float  v_s[D_];           // 2 KB (1/v)
    __shared__ float2 part[4][256];      // 8 KB
    __shared__ float2 wred[4];
    __shared__ float  a_s[TB][256];      // 2 KB
    __shared__ float  mixp[4][TB][D_];   // 16 KB

    if (tid < 512) {
        w_s[0][tid] = Hb[(size_t)(b * T_ + t0 + 0) * D_ + tid];
        w_s[1][tid] = Hb[(size_t)(b * T_ + t0 + 1) * D_ + tid];
        float iv = __builtin_amdgcn_rcpf(v[tid]);
        v_s[tid] = fminf(fmaxf(iv, -1e30f), 1e30f);
    }
    __syncthreads();

    float acc0 = 0.f, acc1 = 0.f;
    const uint4* wb4 = (const uint4*)(Wb + ((size_t)(b * 64 + h * 16) * 256 + s) * 8);

    #pragma unroll 4
    for (int dd = 0; dd < 16; ++dd) {
        uint4 ww = wb4[(size_t)dd * 256];   // 16B coalesced across s-lanes
        float W[8];
        W[0] = asf(ww.x << 16); W[1] = asf(ww.x & 0xffff0000u);
        W[2] = asf(ww.y << 16); W[3] = asf(ww.y & 0xffff0000u);
        W[4] = asf(ww.z << 16); W[5] = asf(ww.z & 0xffff0000u);
        W[6] = asf(ww.w << 16); W[7] = asf(ww.w & 0xffff0000u);

        const int dbase = (h * 16 + dd) * 8;
        float4 iva = *(const float4*)&v_s[dbase];
        float4 ivb = *(const float4*)&v_s[dbase + 4];
        float4 h0a = *(const float4*)&w_s[0][dbase];
        float4 h0b = *(const float4*)&w_s[0][dbase + 4];
        float4 h1a = *(const float4*)&w_s[1][dbase];
        float4 h1b = *(const float4*)&w_s[1][dbase + 4];
        float IV[8] = {iva.x, iva.y, iva.z, iva.w, ivb.x, ivb.y, ivb.z, ivb.w};
        float H0[8] = {h0a.x, h0a.y, h0a.z, h0a.w, h0b.x, h0b.y, h0b.z, h0b.w};
        float H1[8] = {h1a.x, h1a.y, h1a.z, h1a.w, h1b.x, h1b.y, h1b.z, h1b.w};
        #pragma unroll
        for (int p = 0; p < 4; ++p) {
            float W0 = W[2 * p], W1 = W[2 * p + 1];
            float i0 = IV[2 * p], i1 = IV[2 * p + 1];
            float x00 = fmaf(H0[2 * p], W0, i0), x01 = fmaf(H0[2 * p + 1], W1, i1);
            acc0 = fmaf(x00 + x01, __builtin_amdgcn_rcpf(x00 * x01), acc0);
            float x10 = fmaf(H1[2 * p], W0, i0), x11 = fmaf(H1[2 * p + 1], W1, i1);
            acc1 = fmaf(x10 + x11, __builtin_amdgcn_rcpf(x10 * x11), acc1);
        }
    }
    part[h][s] = make_float2(acc0, acc1);
    __syncthreads();

    float p0 = 0.f, p1 = 0.f;
    if (tid < 256) {
        float A0 = part[0][tid].x + part[1][tid].x + part[2][tid].x + part[3][tid].x;
        float A1 = part[0][tid].y + part[1][tid].y + part[2][tid].y + part[3][tid].y;
        float keep = 1.0f - (float)mask[b * S_ + tid];
        p0 = __builtin_amdgcn_exp2f(-C2F * A0) * keep;
        p1 = __builtin_amdgcn_exp2f(-C2F * A1) * keep;
        float s0 = p0, s1 = p1;
        #pragma unroll
        for (int off = 1; off < 64; off <<= 1) {
            s0 += __shfl_xor(s0, off);
            s1 += __shfl_xor(s1, off);
        }
        if ((tid & 63) == 0) wred[tid >> 6] = make_float2(s0, s1);
    }
    __syncthreads();

    if (tid < 256) {
        float den0 = wred[0].x + wred[1].x + wred[2].x + wred[3].x;
        float den1 = wred[0].y + wred[1].y + wred[2].y + wred[3].y;
        float a0 = p0 * __builtin_amdgcn_rcpf(den0);
        float a1 = p1 * __builtin_amdgcn_rcpf(den1);
        attn_out[(size_t)(b * T_ + t0 + 0) * S_ + tid] = a0;
        attn_out[(size_t)(b * T_ + t0 + 1) * S_ + tid] = a1;
        a_s[0][tid] = a0;
        a_s[1][tid] = a1;
    }
    __syncthreads();

    // out-projection: thread (d2=tid&255 -> d={2d2,2d2+1}), s-quarter h
    const int d2 = tid & 255;
    const int sh = h * 64;
    const unsigned short* cw = CWb + ((size_t)(b * S_) + sh) * D_ + 2 * d2;
    float m[TB][2] = {};
    #pragma unroll 8
    for (int s2 = 0; s2 < 64; ++s2) {
        unsigned int cc = *(const unsigned int*)(cw + (size_t)s2 * D_);
        float c0 = asf(cc << 16), c1 = asf(cc & 0xffff0000u);
        #pragma unroll
        for (int t = 0; t < TB; ++t) {
            float a = a_s[t][sh + s2];
            m[t][0] = fmaf(a, c0, m[t][0]);
            m[t][1] = fmaf(a, c1, m[t][1]);
        }
    }
    #pragma unroll
    for (int t = 0; t < TB; ++t) {
        mixp[h][t][2 * d2]     = m[t][0];
        mixp[h][t][2 * d2 + 1] = m[t][1];
    }
    __syncthreads();

    {   // 1024 threads cover TB*512 outputs
        const int t = tid >> 9, d = tid & 511;
        size_t idx = (size_t)(b * T_ + t0 + t) * D_ + d;
        out[idx] = mixp[0][t][d] + mixp[1][t][d] + mixp[2][t][d] + mixp[3][t][d]
                 + OB[idx];
    }
}

extern "C" void kernel_launch(void* const* d_in, const int* in_sizes, int n_in,
                              void* d_out, int out_size, void* d_ws, size_t ws_size,
                              hipStream_t stream) {
    const float* output  = (const float*)d_in[0];
    const float* context = (const float*)d_in[1];
    const int*   mask    = (const int*)d_in[2];
    const float* Wq      = (const float*)d_in[3];
    const float* bq      = (const float*)d_in[4];
    const float* Wc      = (const float*)d_in[5];
    const float* v       = (const float*)d_in[6];
    const float* Wout    = (const float*)d_in[7];
    const float* bout    = (const float*)d_in[8];

    float* out  = (float*)d_out;                       // (B,T,D)
    float* attn = out + (size_t)B_ * T_ * D_;          // (B,T,S)

    char* ws = (char*)d_ws;
    float* Hb             = (float*)ws;                             // 2 MB
    float* OB             = (float*)(ws + (2u << 20));              // 2 MB
    unsigned short* Wb    = (unsigned short*)(ws + (4u << 20));     // 1 MB
    unsigned short* out_f = (unsigned short*)(ws + (6u << 20));     // 1 MB
    unsigned short* ctx_f = (unsigned short*)(ws + (7u << 20));     // 1 MB
    unsigned short* Wq_f  = (unsigned short*)(ws + (8u << 20));     // 0.5 MB
    unsigned short* Wc_f  = (unsigned short*)(ws + (8u << 20) + (512u << 10));
    unsigned short* WoT_f = (unsigned short*)(ws + (9u << 20));     // 0.5 MB
    unsigned short* WoB_f = (unsigned short*)(ws + (9u << 20) + (512u << 10));
    unsigned short* CWb   = (unsigned short*)(ws + (10u << 20));    // 1 MB

    dim3 blk(256);

    prep<<<dim3(16, 16, 6), blk, 0, stream>>>(
        output, context, Wq, Wc, Wout, out_f, ctx_f, Wq_f, Wc_f, WoT_f, WoB_f);

    // four independent GEMMs, one dispatch (z-slices), K=512 each:
    //   z0: Hb  = clamp(exp2(C2*(output@Wq + bq)))        [mode 1]
    //   z1: Wb  = bf16 clamp(exp2(C2*(context@Wc))/v)     [mode 3]
    //   z2: OB  = output@Wout_bot + bout                  [mode 4]
    //   z3: CWb = bf16 context@Wout_top                   [mode 5]
    GArgs gwq = { out_f, Wq_f,  bq,   Hb,  1 };
    GArgs guh = { ctx_f, Wc_f,  v,    Wb,  3 };
    GArgs gob = { out_f, WoB_f, bout, OB,  4 };
    GArgs gcw = { ctx_f, WoT_f, NULL, CWb, 5 };
    gemm2<<<dim3(16, 16, 4), blk, 0, stream>>>(gwq, guh, gob, gcw);

    attn_fused<<<dim3(B_ * T_ / TB), dim3(1024), 0, stream>>>(
        Hb, Wb, CWb, OB, mask, v, attn, out);
}

// Round 4
// 111.852 us; speedup vs baseline: 1.0932x; 1.0101x over previous
//
#include <hip/hip_runtime.h>
#include <hip/hip_bf16.h>

#define B_ 4
#define T_ 256
#define S_ 256
#define D_ 512
#define TB 2   // t's per attention block

typedef __bf16 bf16x8 __attribute__((ext_vector_type(8)));
typedef float  floatx4 __attribute__((ext_vector_type(4)));

#define C2F 2.885390081777926f  // 2*log2(e)

static __device__ __forceinline__ unsigned short f2bf(float x) {
    __hip_bfloat16 h = __float2bfloat16(x);
    return *reinterpret_cast<unsigned short*>(&h);
}
static __device__ __forceinline__ float asf(unsigned int u) {
    float f; __builtin_memcpy(&f, &u, 4); return f;
}
static __device__ __forceinline__ float clamp_pos(float x) {
    // keep strictly positive and finite: [1e-15, 1e15]
    return fminf(fmaxf(x, 1e-15f), 1e15f);
}

// ---------------------------------------------------------------------------
// Fragment-order layout (K=512 => 16 k-blocks of 32):
//   tile(mblk,kblk) = mblk*16 + kblk;  lane = (m&15) | (((k>>3)&3)<<4)
//   addr = (tile*64 + lane)*8 + (k&7)
// ---------------------------------------------------------------------------

__global__ __launch_bounds__(256) void prep(
    const float* __restrict__ output, const float* __restrict__ context,
    const float* __restrict__ Wq, const float* __restrict__ Wc,
    const float* __restrict__ Wout,
    unsigned short* __restrict__ out_f, unsigned short* __restrict__ ctx_f,
    unsigned short* __restrict__ Wq_f, unsigned short* __restrict__ Wc_f,
    unsigned short* __restrict__ WoT_f, unsigned short* __restrict__ WoB_f)
{
    const int tid = threadIdx.x;
    const int z = blockIdx.z;

    if (z >= 4) {
        const float* src = (z == 4) ? output : context;
        unsigned short* dst = (z == 4) ? out_f : ctx_f;
        const int bid  = blockIdx.y * 16 + blockIdx.x;   // 0..255
        const int tile = bid * 4 + (tid >> 6);           // 0..1023
        const int lane = tid & 63;
        const int mblk = tile >> 4, kblk = tile & 15;
        const float* s = src + (size_t)(mblk * 16 + (lane & 15)) * 512
                             + kblk * 32 + (lane >> 4) * 8;
        float4 a = *(const float4*)s;
        float4 b = *(const float4*)(s + 4);
        uint4 pk;
        pk.x = (unsigned)f2bf(a.x) | ((unsigned)f2bf(a.y) << 16);
        pk.y = (unsigned)f2bf(a.z) | ((unsigned)f2bf(a.w) << 16);
        pk.z = (unsigned)f2bf(b.x) | ((unsigned)f2bf(b.y) << 16);
        pk.w = (unsigned)f2bf(b.z) | ((unsigned)f2bf(b.w) << 16);
        *(uint4*)(dst + (size_t)tile * 512 + lane * 8) = pk;
        return;
    }

    const float* W; unsigned short* WF; int krow0;
    if      (z == 0) { W = Wq;   WF = Wq_f;  krow0 = 0;   }
    else if (z == 1) { W = Wc;   WF = Wc_f;  krow0 = 0;   }
    else if (z == 2) { W = Wout; WF = WoT_f; krow0 = 0;   }
    else             { W = Wout; WF = WoB_f; krow0 = 512; }

    const int n0 = blockIdx.x * 32;
    const int k0 = blockIdx.y * 32;

    __shared__ float tile[32][33];
    const int c = tid & 31, r = tid >> 5;
    #pragma unroll
    for (int i = 0; i < 4; ++i)
        tile[r + 8 * i][c] = W[(size_t)(krow0 + k0 + r + 8 * i) * 512 + n0 + c];
    __syncthreads();
    #pragma unroll
    for (int i = 0; i < 4; ++i) {
        const int n = n0 + r + 8 * i;
        const int k = k0 + c;
        const int tl = (n >> 4) * 16 + (k >> 5);
        const int ln = (n & 15) | (((k >> 3) & 3) << 4);
        WF[((size_t)tl * 64 + ln) * 8 + (k & 7)] = f2bf(tile[c][r + 8 * i]);
    }
}

// ---------------------------------------------------------------------------
// MFMA bf16 GEMM from fragment-order inputs. Epilogue modes:
//   1: H = clamp(exp2(C2F*(acc+bq[col])), 1e-15, 1e15)  fp32 (B,T,D)
//   3: W = clamp(exp2(+C2F*acc) * rcp(v[col]), +-1e20)  bf16
//      -> layout [b][d>>3][s][8]   (W = e^{2u}/v;  v*sigmoid = 1/(1/v + H*W))
//   4: fp32 acc + aux[col]                 (OB = output@Wout_bot + bout)
//   5: bf16 acc, natural [row][col]        (CWb = context@Wout_top)
// ---------------------------------------------------------------------------
struct GArgs {
    const unsigned short* Af;
    const unsigned short* Bf;
    const float* aux;    // bias (modes 1,4) or v (mode 3)
    void* C;
    int mode;
};

__global__ __launch_bounds__(256) void gemm2(GArgs g0, GArgs g1, GArgs g2, GArgs g3)
{
    const int z = blockIdx.z;
    GArgs g = (z == 0) ? g0 : (z == 1) ? g1 : (z == 2) ? g2 : g3;

    const int tid  = threadIdx.x;
    const int wave = tid >> 6, lane = tid & 63;
    const int l15  = lane & 15, quad = lane >> 4;
    const int mblk = blockIdx.y * 4 + wave;      // 0..63
    const int nb0  = blockIdx.x * 2;             // 0..30

    const unsigned short* Ap  = g.Af + ((size_t)mblk * 16 * 64 + lane) * 8;
    const unsigned short* Bp0 = g.Bf + ((size_t)nb0 * 16 * 64 + lane) * 8;
    const unsigned short* Bp1 = Bp0 + (size_t)16 * 64 * 8;

    floatx4 acc[2];
    acc[0] = (floatx4){0.f, 0.f, 0.f, 0.f};
    acc[1] = (floatx4){0.f, 0.f, 0.f, 0.f};

    #pragma unroll 4
    for (int k = 0; k < 16; ++k) {
        bf16x8 a  = *(const bf16x8*)(Ap  + k * 512);
        bf16x8 b0 = *(const bf16x8*)(Bp0 + k * 512);
        bf16x8 b1 = *(const bf16x8*)(Bp1 + k * 512);
        acc[0] = __builtin_amdgcn_mfma_f32_16x16x32_bf16(a, b0, acc[0], 0, 0, 0);
        acc[1] = __builtin_amdgcn_mfma_f32_16x16x32_bf16(a, b1, acc[1], 0, 0, 0);
    }

    #pragma unroll
    for (int ni = 0; ni < 2; ++ni) {
        const int col = (nb0 + ni) * 16 + l15;
        const int rbase = mblk * 16 + quad * 4;
        if (g.mode == 1) {
            float* Cf = (float*)g.C;
            float bv = g.aux[col];
            #pragma unroll
            for (int r = 0; r < 4; ++r) {
                float hh = __builtin_amdgcn_exp2f(C2F * (acc[ni][r] + bv));
                Cf[(size_t)(rbase + r) * 512 + col] = clamp_pos(hh);
            }
        } else if (g.mode == 3) {
            unsigned short* Cb = (unsigned short*)g.C;
            float rv = __builtin_amdgcn_rcpf(g.aux[col]);   // 1/v_col
            rv = fminf(fmaxf(rv, -1e30f), 1e30f);
            #pragma unroll
            for (int r = 0; r < 4; ++r) {
                int row = rbase + r, bb = row >> 8, ss = row & 255;
                float ww = __builtin_amdgcn_exp2f(C2F * acc[ni][r]) * rv;
                ww = fminf(fmaxf(ww, -1e20f), 1e20f);
                Cb[((size_t)(bb * 64 + (col >> 3)) * 256 + ss) * 8 + (col & 7)]
                    = f2bf(ww);
            }
        } else if (g.mode == 5) {
            unsigned short* Cb = (unsigned short*)g.C;
            #pragma unroll
            for (int r = 0; r < 4; ++r)
                Cb[(size_t)(rbase + r) * 512 + col] = f2bf(acc[ni][r]);
        } else {   // mode 4
            float* Cf = (float*)g.C;
            float bv = g.aux[col];
            #pragma unroll
            for (int r = 0; r < 4; ++r)
                Cf[(size_t)(rbase + r) * 512 + col] = acc[ni][r] + bv;
        }
    }
}

// ---------------------------------------------------------------------------
// Fused score + masked softmax + out-projection. 512 threads (8 waves),
// 512 blocks -> 4 blocks/CU resident (32 waves/CU): latency hiding across
// barriers, which the old 1024-thread shape (38% occupancy) couldn't get.
// Score: v*sigmoid(-2(w+u)) = 1/(1/v + H*W),  H=e^{2w} (t,d), W=e^{2u}/v (s,d).
// x = iv + H*W is single-signed -> no cancellation. Pair combine, ONE rcp:
//   1/x0 + 1/x1 = (x0+x1) * rcp(x0*x1)
// Thread (s=tid&255, h=tid>>8) owns d-HALF [256h, 256h+256) in score.
// Softmax: p = exp2(-C2F*A) directly (shift-invariance).
// Out-proj: thread owns 4 consecutive d's x one s-quarter -> 8B/lane loads.
// XCD swizzle: chunk so each XCD keeps one b-half's streams in its L2.
// ---------------------------------------------------------------------------
__global__ __launch_bounds__(512, 8) void attn_fused(
    const float* __restrict__ Hb,             // (B,T,D) fp32  e^{2w}
    const unsigned short* __restrict__ Wb,    // (B,D/8,S,8) bf16  e^{2u}/v
    const unsigned short* __restrict__ CWb,   // (B,S,D) bf16
    const float* __restrict__ OB,             // (B,T,D) fp32
    const int*   __restrict__ mask,           // (B,S)
    const float* __restrict__ v,              // (D)
    float* __restrict__ attn_out,             // (B,T,S) fp32
    float* __restrict__ out)                  // (B,T,D) fp32
{
    // bijective XCD chunk swizzle (512 % 8 == 0)
    const int bid = blockIdx.x;
    const int bg  = (bid & 7) * (B_ * T_ / TB / 8) + (bid >> 3);
    const int b   = bg / (T_ / TB);
    const int t0  = (bg % (T_ / TB)) * TB;
    const int tid = threadIdx.x;
    const int s   = tid & 255;
    const int h   = tid >> 8;    // 0..1  (d-half in score)

    __shared__ float  w_s[TB][D_];       // 4 KB (H rows)
    __shared__ float  v_s[D_];           // 2 KB (1/v)
    __shared__ float2 part[2][256];      // 4 KB
    __shared__ float2 wred[4];
    __shared__ float  a_s[TB][256];      // 2 KB
    __shared__ float  mixp[4][TB][D_];   // 16 KB

    w_s[0][tid] = Hb[(size_t)(b * T_ + t0 + 0) * D_ + tid];
    w_s[1][tid] = Hb[(size_t)(b * T_ + t0 + 1) * D_ + tid];
    {
        float iv = __builtin_amdgcn_rcpf(v[tid]);
        v_s[tid] = fminf(fmaxf(iv, -1e30f), 1e30f);
    }
    __syncthreads();

    float acc0 = 0.f, acc1 = 0.f;
    const uint4* wb4 = (const uint4*)(Wb + ((size_t)(b * 64 + h * 32) * 256 + s) * 8);

    #pragma unroll 4
    for (int dd = 0; dd < 32; ++dd) {
        uint4 ww = wb4[(size_t)dd * 256];   // 16B coalesced across s-lanes
        float W[8];
        W[0] = asf(ww.x << 16); W[1] = asf(ww.x & 0xffff0000u);
        W[2] = asf(ww.y << 16); W[3] = asf(ww.y & 0xffff0000u);
        W[4] = asf(ww.z << 16); W[5] = asf(ww.z & 0xffff0000u);
        W[6] = asf(ww.w << 16); W[7] = asf(ww.w & 0xffff0000u);

        const int dbase = (h * 32 + dd) * 8;
        float4 iva = *(const float4*)&v_s[dbase];
        float4 ivb = *(const float4*)&v_s[dbase + 4];
        float4 h0a = *(const float4*)&w_s[0][dbase];
        float4 h0b = *(const float4*)&w_s[0][dbase + 4];
        float4 h1a = *(const float4*)&w_s[1][dbase];
        float4 h1b = *(const float4*)&w_s[1][dbase + 4];
        float IV[8] = {iva.x, iva.y, iva.z, iva.w, ivb.x, ivb.y, ivb.z, ivb.w};
        float H0[8] = {h0a.x, h0a.y, h0a.z, h0a.w, h0b.x, h0b.y, h0b.z, h0b.w};
        float H1[8] = {h1a.x, h1a.y, h1a.z, h1a.w, h1b.x, h1b.y, h1b.z, h1b.w};
        #pragma unroll
        for (int p = 0; p < 4; ++p) {
            float W0 = W[2 * p], W1 = W[2 * p + 1];
            float i0 = IV[2 * p], i1 = IV[2 * p + 1];
            float x00 = fmaf(H0[2 * p], W0, i0), x01 = fmaf(H0[2 * p + 1], W1, i1);
            acc0 = fmaf(x00 + x01, __builtin_amdgcn_rcpf(x00 * x01), acc0);
            float x10 = fmaf(H1[2 * p], W0, i0), x11 = fmaf(H1[2 * p + 1], W1, i1);
            acc1 = fmaf(x10 + x11, __builtin_amdgcn_rcpf(x10 * x11), acc1);
        }
    }
    part[h][s] = make_float2(acc0, acc1);
    __syncthreads();

    float p0 = 0.f, p1 = 0.f;
    if (tid < 256) {
        float A0 = part[0][tid].x + part[1][tid].x;
        float A1 = part[0][tid].y + part[1][tid].y;
        float keep = 1.0f - (float)mask[b * S_ + tid];
        p0 = __builtin_amdgcn_exp2f(-C2F * A0) * keep;
        p1 = __builtin_amdgcn_exp2f(-C2F * A1) * keep;
        float s0 = p0, s1 = p1;
        #pragma unroll
        for (int off = 1; off < 64; off <<= 1) {
            s0 += __shfl_xor(s0, off);
            s1 += __shfl_xor(s1, off);
        }
        if ((tid & 63) == 0) wred[tid >> 6] = make_float2(s0, s1);
    }
    __syncthreads();

    if (tid < 256) {
        float den0 = wred[0].x + wred[1].x + wred[2].x + wred[3].x;
        float den1 = wred[0].y + wred[1].y + wred[2].y + wred[3].y;
        float a0 = p0 * __builtin_amdgcn_rcpf(den0);
        float a1 = p1 * __builtin_amdgcn_rcpf(den1);
        attn_out[(size_t)(b * T_ + t0 + 0) * S_ + tid] = a0;
        attn_out[(size_t)(b * T_ + t0 + 1) * S_ + tid] = a1;
        a_s[0][tid] = a0;
        a_s[1][tid] = a1;
    }
    __syncthreads();

    // out-projection: thread (dq=tid&127 -> d=4dq..4dq+3), s-quarter sq=tid>>7
    const int dq = tid & 127, sq = tid >> 7;
    const int sh = sq * 64;
    const unsigned short* cw = CWb + ((size_t)(b * S_) + sh) * D_ + 4 * dq;
    float m[TB][4] = {};
    #pragma unroll 8
    for (int s2 = 0; s2 < 64; ++s2) {
        uint2 cc = *(const uint2*)(cw + (size_t)s2 * D_);   // 8B coalesced
        float c0 = asf(cc.x << 16), c1 = asf(cc.x & 0xffff0000u);
        float c2 = asf(cc.y << 16), c3 = asf(cc.y & 0xffff0000u);
        #pragma unroll
        for (int t = 0; t < TB; ++t) {
            float a = a_s[t][sh + s2];
            m[t][0] = fmaf(a, c0, m[t][0]);
            m[t][1] = fmaf(a, c1, m[t][1]);
            m[t][2] = fmaf(a, c2, m[t][2]);
            m[t][3] = fmaf(a, c3, m[t][3]);
        }
    }
    #pragma unroll
    for (int t = 0; t < TB; ++t)
        *(float4*)&mixp[sq][t][4 * dq] = make_float4(m[t][0], m[t][1], m[t][2], m[t][3]);
    __syncthreads();

    {   // 512 threads cover TB*512 outputs (2 per thread)
        #pragma unroll
        for (int t = 0; t < TB; ++t) {
            const int d = tid;
            size_t idx = (size_t)(b * T_ + t0 + t) * D_ + d;
            out[idx] = mixp[0][t][d] + mixp[1][t][d] + mixp[2][t][d] + mixp[3][t][d]
                     + OB[idx];
        }
    }
}

extern "C" void kernel_launch(void* const* d_in, const int* in_sizes, int n_in,
                              void* d_out, int out_size, void* d_ws, size_t ws_size,
                              hipStream_t stream) {
    const float* output  = (const float*)d_in[0];
    const float* context = (const float*)d_in[1];
    const int*   mask    = (const int*)d_in[2];
    const float* Wq      = (const float*)d_in[3];
    const float* bq      = (const float*)d_in[4];
    const float* Wc      = (const float*)d_in[5];
    const float* v       = (const float*)d_in[6];
    const float* Wout    = (const float*)d_in[7];
    const float* bout    = (const float*)d_in[8];

    float* out  = (float*)d_out;                       // (B,T,D)
    float* attn = out + (size_t)B_ * T_ * D_;          // (B,T,S)

    char* ws = (char*)d_ws;
    float* Hb             = (float*)ws;                             // 2 MB
    float* OB             = (float*)(ws + (2u << 20));              // 2 MB
    unsigned short* Wb    = (unsigned short*)(ws + (4u << 20));     // 1 MB
    unsigned short* out_f = (unsigned short*)(ws + (6u << 20));     // 1 MB
    unsigned short* ctx_f = (unsigned short*)(ws + (7u << 20));     // 1 MB
    unsigned short* Wq_f  = (unsigned short*)(ws + (8u << 20));     // 0.5 MB
    unsigned short* Wc_f  = (unsigned short*)(ws + (8u << 20) + (512u << 10));
    unsigned short* WoT_f = (unsigned short*)(ws + (9u << 20));     // 0.5 MB
    unsigned short* WoB_f = (unsigned short*)(ws + (9u << 20) + (512u << 10));
    unsigned short* CWb   = (unsigned short*)(ws + (10u << 20));    // 1 MB

    dim3 blk(256);

    prep<<<dim3(16, 16, 6), blk, 0, stream>>>(
        output, context, Wq, Wc, Wout, out_f, ctx_f, Wq_f, Wc_f, WoT_f, WoB_f);

    // four independent GEMMs, one dispatch (z-slices), K=512 each:
    //   z0: Hb  = clamp(exp2(C2*(output@Wq + bq)))        [mode 1]
    //   z1: Wb  = bf16 clamp(exp2(C2*(context@Wc))/v)     [mode 3]
    //   z2: OB  = output@Wout_bot + bout                  [mode 4]
    //   z3: CWb = bf16 context@Wout_top                   [mode 5]
    GArgs gwq = { out_f, Wq_f,  bq,   Hb,  1 };
    GArgs guh = { ctx_f, Wc_f,  v,    Wb,  3 };
    GArgs gob = { out_f, WoB_f, bout, OB,  4 };
    GArgs gcw = { ctx_f, WoT_f, NULL, CWb, 5 };
    gemm2<<<dim3(16, 16, 4), blk, 0, stream>>>(gwq, guh, gob, gcw);

    attn_fused<<<dim3(B_ * T_ / TB), dim3(512), 0, stream>>>(
        Hb, Wb, CWb, OB, mask, v, attn, out);
}